// Round 9
// baseline (571.821 us; speedup 1.0000x reference)
//
#include <hip/hip_runtime.h>

typedef unsigned short u16;
typedef unsigned int u32;

#define SEQ 96
#define DM 512
#define NBATCH 512
#define NFREQ 49
#define CUT 16
#define MROWS (NBATCH * SEQ)  // 49152

typedef __attribute__((ext_vector_type(8))) short bf16x8;
typedef __attribute__((ext_vector_type(8))) unsigned short u16x8;
typedef __attribute__((ext_vector_type(4))) float f32x4;

// ---------- bf16 helpers (manual, RNE) ----------
__device__ __forceinline__ u16 f2bf(float f) {
  u32 u = __float_as_uint(f);
  u32 r = (u + 0x7fffu + ((u >> 16) & 1u)) >> 16;
  return (u16)r;
}
__device__ __forceinline__ float bf2f(u16 u) {
  return __uint_as_float(((u32)u) << 16);
}

// async global->LDS, 16B per lane. lds ptr must be wave-uniform base.
__device__ __forceinline__ void g2l16(const void* g, void* l) {
  __builtin_amdgcn_global_load_lds(
      (const __attribute__((address_space(1))) void*)g,
      (__attribute__((address_space(3))) void*)l, 16, 0, 0);
}

// ---------- K1: build spectral filter matrices Fl/Fh [96x96] bf16 ----------
__global__ void build_filters_k(const float* __restrict__ w,
                                u16* __restrict__ FlB, u16* __restrict__ FhB) {
  int idx = blockIdx.x * 256 + threadIdx.x;
  if (idx >= SEQ * SEQ) return;
  int s = idx / SEQ, t = idx % SEQ;
  int d = s - t;
  const float scale = 1.0f / (float)SEQ;
  const float w0 = 6.283185307179586f / (float)SEQ;
  float cl = 0.f, ch = 0.f;
  for (int k = 0; k < NFREQ; k++) {
    int m = (k * d) % SEQ;
    if (m < 0) m += SEQ;
    float c = (k == 0 || k == SEQ / 2) ? 1.0f : 2.0f;
    float v = c * w[k] * cosf(w0 * (float)m) * scale;
    if (k < CUT) cl += v; else ch += v;
  }
  FlB[idx] = f2bf(cl);
  FhB[idx] = f2bf(ch);
}

// ---------- K1b: transpose fp32 [K,N] weight -> bf16 [N,K]; optional raw cast ----------
__global__ void __launch_bounds__(256) transpose_w_k(
    const float* __restrict__ W, u16* __restrict__ Wt, int K, int N,
    u16* __restrict__ WB) {
  __shared__ float t[32][33];
  int k0 = blockIdx.x * 32, n0 = blockIdx.y * 32;
  int tx = threadIdx.x & 31, ty = threadIdx.x >> 5;  // ty 0..7
  #pragma unroll
  for (int r = 0; r < 32; r += 8) {
    float v = W[(size_t)(k0 + ty + r) * N + n0 + tx];
    t[ty + r][tx] = v;
    if (WB) WB[(size_t)(k0 + ty + r) * N + n0 + tx] = f2bf(v);
  }
  __syncthreads();
  #pragma unroll
  for (int r = 0; r < 32; r += 8)
    Wt[(size_t)(n0 + ty + r) * K + k0 + tx] = f2bf(t[tx][ty + r]);
}

// ---------- K1c: Wgc[n][k<512]=W1t, [k>=512]=W2t where W1=Wl@Wg_top etc ----------
// C[n][k] = sum_e Wgt[n][zoff+e] * WB[k][e]  (A rows = Wg_half^T, B rows = Wl/Wh bf16)
__global__ void __launch_bounds__(256) wgc_build_k(
    const u16* __restrict__ Wgt, const u16* __restrict__ WlB,
    const u16* __restrict__ WhB, u16* __restrict__ Wgc) {
  __shared__ __align__(16) u16 As[128 * 32];
  __shared__ __align__(16) u16 Bs[128 * 32];
  const int n0 = blockIdx.x * 128;
  const int k0 = blockIdx.y * 128;
  const int zoff = blockIdx.z ? 512 : 0;
  const u16* WB = blockIdx.z ? WhB : WlB;
  const int tid = threadIdx.x;
  const int lane = tid & 63;
  const int w = tid >> 6;
  const int wm = w & 1, wn = w >> 1;
  const int l15 = lane & 15;
  const int lq = lane >> 4;

  f32x4 acc[4][4] = {};

  for (int kt = 0; kt < 512; kt += 32) {  // e-loop
    #pragma unroll
    for (int r = 0; r < 2; r++) {
      int chunk = r * 256 + tid;
      int row = chunk >> 2;
      int ce = (chunk & 3) << 3;
      u32 lo = (u32)((r * 256 + w * 64) << 4);
      g2l16(Wgt + (size_t)(n0 + row) * 1024 + zoff + kt + ce, (char*)As + lo);
      g2l16(WB + (size_t)(k0 + row) * 512 + kt + ce, (char*)Bs + lo);
    }
    __syncthreads();
    bf16x8 af[4], bf[4];
    #pragma unroll
    for (int i = 0; i < 4; i++)
      af[i] = *(const bf16x8*)&As[(wm * 64 + i * 16 + l15) * 32 + lq * 8];
    #pragma unroll
    for (int j = 0; j < 4; j++)
      bf[j] = *(const bf16x8*)&Bs[(wn * 64 + j * 16 + l15) * 32 + lq * 8];
    #pragma unroll
    for (int i = 0; i < 4; i++)
      #pragma unroll
      for (int j = 0; j < 4; j++)
        acc[i][j] = __builtin_amdgcn_mfma_f32_16x16x32_bf16(af[i], bf[j], acc[i][j], 0, 0, 0);
    __syncthreads();
  }

  #pragma unroll
  for (int j = 0; j < 4; j++) {
    int kcol = k0 + wn * 64 + j * 16 + l15;
    #pragma unroll
    for (int i = 0; i < 4; i++) {
      int nrow = n0 + wm * 64 + i * 16 + lq * 4;
      #pragma unroll
      for (int r = 0; r < 4; r++)
        Wgc[(size_t)(nrow + r) * 1024 + zoff + kcol] = f2bf(acc[i][j][r]);
    }
  }
}

// ---------- K1d: b2[n] = bg[n] + sum_e bl[e]*Wg[e][n] + bh[e]*Wg[512+e][n] ----------
__global__ void __launch_bounds__(256) b2_k(
    const float* __restrict__ Wg, const float* __restrict__ bl,
    const float* __restrict__ bh, const float* __restrict__ bg,
    float* __restrict__ b2) {
  int n = blockIdx.x * 256 + threadIdx.x;
  float s = bg[n];
  #pragma unroll 4
  for (int e = 0; e < 512; e++) {
    s += bl[e] * Wg[(size_t)e * 512 + n];
    s += bh[e] * Wg[(size_t)(512 + e) * 512 + n];
  }
  b2[n] = s;
}

// ---------- K2: fused transpose + spectral filter (round-5/7 proven version) ----------
__global__ void __launch_bounds__(256) filter_fused_k(
    const float* __restrict__ x, const u16* __restrict__ FlB,
    const u16* __restrict__ FhB, u16* __restrict__ xl, u16* __restrict__ xh) {
  __shared__ __align__(16) u16 Bs[128 * SEQ];        // [128 d][96 t], 24.0 KB
  __shared__ __align__(16) u16 As0[2 * SEQ * SEQ];   // [2][96 s][96 t], 36.0 KB
  __shared__ float xs[SEQ * 33];                     // quarter-stage, 12.4 KB
  int tid = threadIdx.x;
  int lane = tid & 63, w = tid >> 6;
  int b = blockIdx.x, d0 = blockIdx.y * 128;

  // stage A (Fl then Fh) async: 2 x 1152 16B-chunks (overlaps the transpose)
  #pragma unroll
  for (int it = 0; it < 9; it++) {
    int c = it * 256 + tid;      // 0..2303
    const u16* src = (c < 1152) ? (FlB + c * 8) : (FhB + (c - 1152) * 8);
    g2l16(src, (char*)As0 + ((it * 256 + w * 64) << 4));
  }

  // build Bs[d][t] from x in 4 quarter-passes of 32 d-columns
  const float* xb = x + (size_t)b * SEQ * DM + d0;
  u32* BsW = (u32*)Bs;
  #pragma unroll
  for (int q = 0; q < 4; q++) {
    #pragma unroll
    for (int v = 0; v < 3; v++) {
      int c = v * 256 + tid;         // 0..767
      int t = c >> 3, f = (c & 7) << 2;
      float4 fv = *(const float4*)(xb + (size_t)t * DM + q * 32 + f);
      xs[t * 33 + f + 0] = fv.x;
      xs[t * 33 + f + 1] = fv.y;
      xs[t * 33 + f + 2] = fv.z;
      xs[t * 33 + f + 3] = fv.w;
    }
    __syncthreads();
    #pragma unroll
    for (int v = 0; v < 6; v++) {
      int c = v * 256 + tid;         // 0..1535
      int dl = c / 48, tw = c % 48;
      u32 lo = (u32)f2bf(xs[(2 * tw) * 33 + dl]);
      u32 hi = (u32)f2bf(xs[(2 * tw + 1) * 33 + dl]);
      BsW[(size_t)(q * 32 + dl) * 48 + tw] = lo | (hi << 16);
    }
    __syncthreads();  // also drains As g2l16 on the last pass
  }

  const int l15 = lane & 15, lq = lane >> 4;
  f32x4 acc[2][6][2] = {};
  #pragma unroll
  for (int ks = 0; ks < 3; ks++) {
    int kt = ks * 32;
    bf16x8 bfr[2];
    #pragma unroll
    for (int j = 0; j < 2; j++)
      bfr[j] = *(const bf16x8*)&Bs[(w * 32 + j * 16 + l15) * SEQ + kt + lq * 8];
    #pragma unroll
    for (int f = 0; f < 2; f++)
      #pragma unroll
      for (int i = 0; i < 6; i++) {
        bf16x8 afr = *(const bf16x8*)&As0[f * SEQ * SEQ + (i * 16 + l15) * SEQ + kt + lq * 8];
        #pragma unroll
        for (int j = 0; j < 2; j++)
          acc[f][i][j] = __builtin_amdgcn_mfma_f32_16x16x32_bf16(afr, bfr[j], acc[f][i][j], 0, 0, 0);
      }
  }
  #pragma unroll
  for (int f = 0; f < 2; f++) {
    u16* dst = f ? xh : xl;
    #pragma unroll
    for (int i = 0; i < 6; i++)
      #pragma unroll
      for (int j = 0; j < 2; j++) {
        int d = d0 + w * 32 + j * 16 + l15;
        #pragma unroll
        for (int r = 0; r < 4; r++) {
          int s = i * 16 + lq * 4 + r;
          dst[((size_t)b * SEQ + s) * DM + d] = f2bf(acc[f][i][j][r]);
        }
      }
  }
}

// ---------- K3: FUSED proj + gate-z GEMM ----------
// Grid (384 m, 4 n), 512 thr (8 waves). Waves 0-3: y-path (yl over kt<512 with
// Wlt, then yh with Wht). Waves 4-7: z-path (K=1024 over Wgc = [W1t|W2t]).
// One A-stage (xl/xh) per K-step serves both paths. 2-barrier proven loop shape.
__global__ void __launch_bounds__(512) fused_pg_k(
    const u16* __restrict__ xl, const u16* __restrict__ xh,
    const u16* __restrict__ Wlt, const u16* __restrict__ Wht,
    const u16* __restrict__ Wgc,
    const float* __restrict__ bl, const float* __restrict__ bh,
    const float* __restrict__ b2,
    u16* __restrict__ yl, u16* __restrict__ yh, u16* __restrict__ g) {
  __shared__ __align__(16) u16 As[128 * 32];
  __shared__ __align__(16) u16 By[128 * 32];
  __shared__ __align__(16) u16 Bz[128 * 32];
  const int m0 = blockIdx.x * 128;
  const int n0 = blockIdx.y * 128;
  const int tid = threadIdx.x;
  const int lane = tid & 63;
  const int w = tid >> 6;            // 0..7
  const bool isY = (w < 4);
  const int wz = w & 3;
  const int wm = wz & 1, wn = wz >> 1;   // 2x2 waves per role, each 64x64
  const int l15 = lane & 15;
  const int lq = lane >> 4;
  const f32x4 fzero = {0.f, 0.f, 0.f, 0.f};

  // staging: 512 threads cover 512 chunks per array in one shot
  const int rowS = tid >> 2;             // 0..127
  const int ce = (tid & 3) << 3;
  const u32 ldsoff = (u32)((w * 64) << 4);

  f32x4 acc[4][4] = {};

  for (int kt = 0; kt < 1024; kt += 32) {
    const u16* Asrc = (kt < 512) ? xl : xh;
    const u16* Bysrc = (kt < 512) ? Wlt : Wht;
    const int ka = kt & 511;
    g2l16(Asrc + (size_t)(m0 + rowS) * 512 + ka + ce, (char*)As + ldsoff);
    g2l16(Bysrc + (size_t)(n0 + rowS) * 512 + ka + ce, (char*)By + ldsoff);
    g2l16(Wgc + (size_t)(n0 + rowS) * 1024 + kt + ce, (char*)Bz + ldsoff);
    __syncthreads();
    const u16* Bsel = isY ? By : Bz;
    bf16x8 af[4], bf[4];
    #pragma unroll
    for (int i = 0; i < 4; i++)
      af[i] = *(const bf16x8*)&As[(wm * 64 + i * 16 + l15) * 32 + lq * 8];
    #pragma unroll
    for (int j = 0; j < 4; j++)
      bf[j] = *(const bf16x8*)&Bsel[(wn * 64 + j * 16 + l15) * 32 + lq * 8];
    #pragma unroll
    for (int i = 0; i < 4; i++)
      #pragma unroll
      for (int j = 0; j < 4; j++)
        acc[i][j] = __builtin_amdgcn_mfma_f32_16x16x32_bf16(af[i], bf[j], acc[i][j], 0, 0, 0);
    // mid-epilogue: yl complete after the kt=480 MFMAs
    if (kt == 480 && isY) {
      #pragma unroll
      for (int j = 0; j < 4; j++) {
        int n = n0 + wn * 64 + j * 16 + l15;
        float bv = bl[n];
        #pragma unroll
        for (int i = 0; i < 4; i++) {
          int mrow = m0 + wm * 64 + i * 16 + lq * 4;
          #pragma unroll
          for (int r = 0; r < 4; r++)
            yl[(size_t)(mrow + r) * 512 + n] = f2bf(acc[i][j][r] + bv);
          acc[i][j] = fzero;
        }
      }
    }
    __syncthreads();
  }

  if (isY) {
    #pragma unroll
    for (int j = 0; j < 4; j++) {
      int n = n0 + wn * 64 + j * 16 + l15;
      float bv = bh[n];
      #pragma unroll
      for (int i = 0; i < 4; i++) {
        int mrow = m0 + wm * 64 + i * 16 + lq * 4;
        #pragma unroll
        for (int r = 0; r < 4; r++)
          yh[(size_t)(mrow + r) * 512 + n] = f2bf(acc[i][j][r] + bv);
      }
    }
  } else {
    #pragma unroll
    for (int j = 0; j < 4; j++) {
      int n = n0 + wn * 64 + j * 16 + l15;
      float bv = b2[n];
      #pragma unroll
      for (int i = 0; i < 4; i++) {
        int mrow = m0 + wm * 64 + i * 16 + lq * 4;
        #pragma unroll
        for (int r = 0; r < 4; r++) {
          float z = acc[i][j][r] + bv;
          g[(size_t)(mrow + r) * 512 + n] = f2bf(1.0f / (1.0f + __expf(-z)));
        }
      }
    }
  }
}

// ---------- fallback K3/K4 (round-0 proven) ----------
__global__ void __launch_bounds__(256) gemm_proj_mfma_k(
    const u16* __restrict__ xl, const u16* __restrict__ xh,
    const u16* __restrict__ Wlt, const u16* __restrict__ Wht,
    const float* __restrict__ bl, const float* __restrict__ bh,
    u16* __restrict__ yl, u16* __restrict__ yh) {
  const u16* A = blockIdx.z ? xh : xl;
  const u16* Bt = blockIdx.z ? Wht : Wlt;
  const float* bias = blockIdx.z ? bh : bl;
  u16* C = blockIdx.z ? yh : yl;

  __shared__ __align__(16) u16 As[128 * 32];
  __shared__ __align__(16) u16 Bs[128 * 32];
  const int m0 = blockIdx.x * 128;
  const int n0 = blockIdx.y * 128;
  const int tid = threadIdx.x;
  const int lane = tid & 63;
  const int w = tid >> 6;
  const int wm = w & 1, wn = w >> 1;
  const int l15 = lane & 15;
  const int lq = lane >> 4;

  f32x4 acc[4][4] = {};

  for (int kt = 0; kt < 512; kt += 32) {
    #pragma unroll
    for (int r = 0; r < 2; r++) {
      int chunk = r * 256 + tid;
      int row = chunk >> 2;
      int ce = (chunk & 3) << 3;
      u32 lo = (u32)((r * 256 + w * 64) << 4);
      g2l16(A + (size_t)(m0 + row) * 512 + kt + ce, (char*)As + lo);
      g2l16(Bt + (size_t)(n0 + row) * 512 + kt + ce, (char*)Bs + lo);
    }
    __syncthreads();
    bf16x8 af[4], bf[4];
    #pragma unroll
    for (int i = 0; i < 4; i++)
      af[i] = *(const bf16x8*)&As[(wm * 64 + i * 16 + l15) * 32 + lq * 8];
    #pragma unroll
    for (int j = 0; j < 4; j++)
      bf[j] = *(const bf16x8*)&Bs[(wn * 64 + j * 16 + l15) * 32 + lq * 8];
    #pragma unroll
    for (int i = 0; i < 4; i++)
      #pragma unroll
      for (int j = 0; j < 4; j++)
        acc[i][j] = __builtin_amdgcn_mfma_f32_16x16x32_bf16(af[i], bf[j], acc[i][j], 0, 0, 0);
    __syncthreads();
  }

  #pragma unroll
  for (int j = 0; j < 4; j++) {
    int n = n0 + wn * 64 + j * 16 + l15;
    float bv = bias[n];
    #pragma unroll
    for (int i = 0; i < 4; i++) {
      int mrow = m0 + wm * 64 + i * 16 + lq * 4;
      #pragma unroll
      for (int r = 0; r < 4; r++)
        C[(size_t)(mrow + r) * 512 + n] = f2bf(acc[i][j][r] + bv);
    }
  }
}

__global__ void __launch_bounds__(256) gemm_gate_mfma_k(
    const u16* __restrict__ yl, const u16* __restrict__ yh,
    const u16* __restrict__ Wgt, const float* __restrict__ bg,
    u16* __restrict__ g) {
  __shared__ __align__(16) u16 As[128 * 32];
  __shared__ __align__(16) u16 Bs[128 * 32];
  const int m0 = blockIdx.x * 128;
  const int n0 = blockIdx.y * 128;
  const int tid = threadIdx.x;
  const int lane = tid & 63;
  const int w = tid >> 6;
  const int wm = w & 1, wn = w >> 1;
  const int l15 = lane & 15;
  const int lq = lane >> 4;

  f32x4 acc[4][4] = {};

  for (int kt = 0; kt < 1024; kt += 32) {
    const u16* Ak = (kt < 512) ? yl : yh;
    int ka = kt & 511;
    #pragma unroll
    for (int r = 0; r < 2; r++) {
      int chunk = r * 256 + tid;
      int row = chunk >> 2;
      int ce = (chunk & 3) << 3;
      u32 lo = (u32)((r * 256 + w * 64) << 4);
      g2l16(Ak + (size_t)(m0 + row) * 512 + ka + ce, (char*)As + lo);
      g2l16(Wgt + (size_t)(n0 + row) * 1024 + kt + ce, (char*)Bs + lo);
    }
    __syncthreads();
    bf16x8 af[4], bf[4];
    #pragma unroll
    for (int i = 0; i < 4; i++)
      af[i] = *(const bf16x8*)&As[(wm * 64 + i * 16 + l15) * 32 + lq * 8];
    #pragma unroll
    for (int j = 0; j < 4; j++)
      bf[j] = *(const bf16x8*)&Bs[(wn * 64 + j * 16 + l15) * 32 + lq * 8];
    #pragma unroll
    for (int i = 0; i < 4; i++)
      #pragma unroll
      for (int j = 0; j < 4; j++)
        acc[i][j] = __builtin_amdgcn_mfma_f32_16x16x32_bf16(af[i], bf[j], acc[i][j], 0, 0, 0);
    __syncthreads();
  }

  #pragma unroll
  for (int j = 0; j < 4; j++) {
    int n = n0 + wn * 64 + j * 16 + l15;
    float bv = bg[n];
    #pragma unroll
    for (int i = 0; i < 4; i++) {
      int mrow = m0 + wm * 64 + i * 16 + lq * 4;
      #pragma unroll
      for (int r = 0; r < 4; r++) {
        float z = acc[i][j][r] + bv;
        g[(size_t)(mrow + r) * 512 + n] = f2bf(1.0f / (1.0f + __expf(-z)));
      }
    }
  }
}

// ---------- K5: y = x + g*yl + (1-g)*yh ; LayerNorm (one wave per row) ----------
__global__ void __launch_bounds__(256) final_ln_k(
    const float* __restrict__ x, const u16* __restrict__ yl,
    const u16* __restrict__ yh, const u16* __restrict__ g,
    const float* __restrict__ gamma, const float* __restrict__ beta,
    float* __restrict__ out) {
  const int wave = threadIdx.x >> 6;
  const int lane = threadIdx.x & 63;
  const size_t row = (size_t)blockIdx.x * 4 + wave;
  const size_t base = row * 512 + lane * 8;
  const int e = lane * 8;

  float4 xv0 = *(const float4*)(x + base);
  float4 xv1 = *(const float4*)(x + base + 4);
  u16x8 lv = *(const u16x8*)(yl + base);
  u16x8 hv = *(const u16x8*)(yh + base);
  u16x8 gv = *(const u16x8*)(g + base);

  float v[8];
  const float xs[8] = {xv0.x, xv0.y, xv0.z, xv0.w, xv1.x, xv1.y, xv1.z, xv1.w};
  float sum = 0.f, sumsq = 0.f;
  #pragma unroll
  for (int k = 0; k < 8; k++) {
    float gl = bf2f(gv[k]);
    float vv = xs[k] + gl * bf2f(lv[k]) + (1.f - gl) * bf2f(hv[k]);
    v[k] = vv;
    sum += vv;
    sumsq += vv * vv;
  }
  #pragma unroll
  for (int off = 32; off; off >>= 1) {
    sum += __shfl_xor(sum, off);
    sumsq += __shfl_xor(sumsq, off);
  }
  const float mu = sum * (1.f / 512.f);
  const float var = sumsq * (1.f / 512.f) - mu * mu;
  const float inv = rsqrtf(var + 1e-5f);

  float4 gm0 = *(const float4*)(gamma + e);
  float4 gm1 = *(const float4*)(gamma + e + 4);
  float4 bt0 = *(const float4*)(beta + e);
  float4 bt1 = *(const float4*)(beta + e + 4);
  float4 o0, o1;
  o0.x = (v[0] - mu) * inv * gm0.x + bt0.x;
  o0.y = (v[1] - mu) * inv * gm0.y + bt0.y;
  o0.z = (v[2] - mu) * inv * gm0.z + bt0.z;
  o0.w = (v[3] - mu) * inv * gm0.w + bt0.w;
  o1.x = (v[4] - mu) * inv * gm1.x + bt1.x;
  o1.y = (v[5] - mu) * inv * gm1.y + bt1.y;
  o1.z = (v[6] - mu) * inv * gm1.z + bt1.z;
  o1.w = (v[7] - mu) * inv * gm1.w + bt1.w;
  *(float4*)(out + base) = o0;
  *(float4*)(out + base + 4) = o1;
}

extern "C" void kernel_launch(void* const* d_in, const int* in_sizes, int n_in,
                              void* d_out, int out_size, void* d_ws, size_t ws_size,
                              hipStream_t stream) {
  const float* x     = (const float*)d_in[0];
  const float* fw    = (const float*)d_in[1];
  const float* Wl    = (const float*)d_in[2];
  const float* bl    = (const float*)d_in[3];
  const float* Wh    = (const float*)d_in[4];
  const float* bh    = (const float*)d_in[5];
  const float* Wg    = (const float*)d_in[6];
  const float* bg    = (const float*)d_in[7];
  const float* gamma = (const float*)d_in[8];
  const float* beta  = (const float*)d_in[9];
  float* out = (float*)d_out;

  char* ws = (char*)d_ws;
  u16* FlB = (u16*)ws;                      // 96*96 bf16
  u16* FhB = FlB + SEQ * SEQ;
  u16* Wlt = (u16*)(ws + 64 * 1024);        // 512x512 bf16 [N][K]
  u16* Wht = Wlt + 512 * 512;
  u16* Wgt = Wht + 512 * 512;               // 512x1024 [N][K]
  u16* WlB = Wgt + 512 * 1024;              // 512x512 bf16 raw [K][N]
  u16* WhB = WlB + 512 * 512;
  u16* Wgc = WhB + 512 * 512;               // 512x1024: [W1t | W2t]
  float* b2 = (float*)(ws + 6 * 1024 * 1024);  // 512 fp32
  size_t tsz = (size_t)MROWS * 512;         // 25165824 elems
  u16* xl = (u16*)(ws + 8 * 1024 * 1024);
  u16* xh = xl + tsz;
  u16* yl = xh + tsz;
  u16* yh = yl + tsz;

  const bool fused = ws_size >= (size_t)8 * 1024 * 1024 + 5 * tsz * sizeof(u16);
  u16* gbuf = fused ? (yh + tsz) : xl;   // fresh buffer when fused (xl stays live)

  build_filters_k<<<dim3(36), dim3(256), 0, stream>>>(fw, FlB, FhB);
  transpose_w_k<<<dim3(16, 16), dim3(256), 0, stream>>>(Wl, Wlt, 512, 512,
                                                        fused ? WlB : nullptr);
  transpose_w_k<<<dim3(16, 16), dim3(256), 0, stream>>>(Wh, Wht, 512, 512,
                                                        fused ? WhB : nullptr);
  transpose_w_k<<<dim3(32, 16), dim3(256), 0, stream>>>(Wg, Wgt, 1024, 512, nullptr);
  filter_fused_k<<<dim3(NBATCH, DM / 128), dim3(256), 0, stream>>>(x, FlB, FhB, xl, xh);

  if (fused) {
    wgc_build_k<<<dim3(4, 4, 2), dim3(256), 0, stream>>>(Wgt, WlB, WhB, Wgc);
    b2_k<<<dim3(2), dim3(256), 0, stream>>>(Wg, bl, bh, bg, b2);
    fused_pg_k<<<dim3(MROWS / 128, 4), dim3(512), 0, stream>>>(
        xl, xh, Wlt, Wht, Wgc, bl, bh, b2, yl, yh, gbuf);
  } else {
    gemm_proj_mfma_k<<<dim3(MROWS / 128, 4, 2), dim3(256), 0, stream>>>(
        xl, xh, Wlt, Wht, bl, bh, yl, yh);
    gemm_gate_mfma_k<<<dim3(MROWS / 128, 4), dim3(256), 0, stream>>>(
        yl, yh, Wgt, bg, gbuf);
  }
  final_ln_k<<<dim3(MROWS / 4), dim3(256), 0, stream>>>(
      x, yl, yh, gbuf, gamma, beta, out);
}

// Round 10
// 439.484 us; speedup vs baseline: 1.3011x; 1.3011x over previous
//
#include <hip/hip_runtime.h>

typedef unsigned short u16;
typedef unsigned int u32;

#define SEQ 96
#define DM 512
#define NBATCH 512
#define NFREQ 49
#define CUT 16
#define MROWS (NBATCH * SEQ)  // 49152

typedef __attribute__((ext_vector_type(8))) short bf16x8;
typedef __attribute__((ext_vector_type(8))) unsigned short u16x8;
typedef __attribute__((ext_vector_type(4))) float f32x4;

// ---------- bf16 helpers (manual, RNE) ----------
__device__ __forceinline__ u16 f2bf(float f) {
  u32 u = __float_as_uint(f);
  u32 r = (u + 0x7fffu + ((u >> 16) & 1u)) >> 16;
  return (u16)r;
}
__device__ __forceinline__ float bf2f(u16 u) {
  return __uint_as_float(((u32)u) << 16);
}

// async global->LDS, 16B per lane. lds ptr must be wave-uniform base.
__device__ __forceinline__ void g2l16(const void* g, void* l) {
  __builtin_amdgcn_global_load_lds(
      (const __attribute__((address_space(1))) void*)g,
      (__attribute__((address_space(3))) void*)l, 16, 0, 0);
}

// ---------- K1: build spectral filter matrices Fl/Fh [96x96] bf16 ----------
__global__ void build_filters_k(const float* __restrict__ w,
                                u16* __restrict__ FlB, u16* __restrict__ FhB) {
  int idx = blockIdx.x * 256 + threadIdx.x;
  if (idx >= SEQ * SEQ) return;
  int s = idx / SEQ, t = idx % SEQ;
  int d = s - t;
  const float scale = 1.0f / (float)SEQ;
  const float w0 = 6.283185307179586f / (float)SEQ;
  float cl = 0.f, ch = 0.f;
  for (int k = 0; k < NFREQ; k++) {
    int m = (k * d) % SEQ;
    if (m < 0) m += SEQ;
    float c = (k == 0 || k == SEQ / 2) ? 1.0f : 2.0f;
    float v = c * w[k] * cosf(w0 * (float)m) * scale;
    if (k < CUT) cl += v; else ch += v;
  }
  FlB[idx] = f2bf(cl);
  FhB[idx] = f2bf(ch);
}

// ---------- K1b: transpose fp32 [K,N] weight -> bf16 [N,K] ----------
__global__ void __launch_bounds__(256) transpose_w_k(
    const float* __restrict__ W, u16* __restrict__ Wt, int K, int N) {
  __shared__ float t[32][33];
  int k0 = blockIdx.x * 32, n0 = blockIdx.y * 32;
  int tx = threadIdx.x & 31, ty = threadIdx.x >> 5;  // ty 0..7
  #pragma unroll
  for (int r = 0; r < 32; r += 8)
    t[ty + r][tx] = W[(size_t)(k0 + ty + r) * N + n0 + tx];
  __syncthreads();
  #pragma unroll
  for (int r = 0; r < 32; r += 8)
    Wt[(size_t)(n0 + ty + r) * K + k0 + tx] = f2bf(t[tx][ty + r]);
}

// ---------- K2: fused transpose + spectral filter ----------
// Staging + MFMA identical to the proven round-5/7 version (As0 LDS-staged,
// quarter-pass transpose). ONLY change: epilogue re-tiles acc through the
// dead Bs+xs LDS region -> fully-coalesced u32 stores (was 96 scattered
// 2B stores/thread = 32B granules for 96 MB of output).
__global__ void __launch_bounds__(256) filter_fused_k(
    const float* __restrict__ x, const u16* __restrict__ FlB,
    const u16* __restrict__ FhB, u16* __restrict__ xl, u16* __restrict__ xh) {
  __shared__ __align__(16) char ldsbuf[24576 + 12672]; // Bs [128][96] | xs [96][33]
  __shared__ __align__(16) u16 As0[2 * SEQ * SEQ];     // [2][96 s][96 t], 36.0 KB
  u16* Bs = (u16*)ldsbuf;
  float* xs = (float*)(ldsbuf + 24576);
  int tid = threadIdx.x;
  int lane = tid & 63, w = tid >> 6;
  int b = blockIdx.x, d0 = blockIdx.y * 128;

  // stage A (Fl then Fh) async: 2 x 1152 16B-chunks (overlaps the transpose)
  #pragma unroll
  for (int it = 0; it < 9; it++) {
    int c = it * 256 + tid;      // 0..2303
    const u16* src = (c < 1152) ? (FlB + c * 8) : (FhB + (c - 1152) * 8);
    g2l16(src, (char*)As0 + ((it * 256 + w * 64) << 4));
  }

  // build Bs[d][t] from x in 4 quarter-passes of 32 d-columns
  const float* xb = x + (size_t)b * SEQ * DM + d0;
  u32* BsW = (u32*)Bs;
  #pragma unroll
  for (int q = 0; q < 4; q++) {
    #pragma unroll
    for (int v = 0; v < 3; v++) {
      int c = v * 256 + tid;         // 0..767
      int t = c >> 3, f = (c & 7) << 2;
      float4 fv = *(const float4*)(xb + (size_t)t * DM + q * 32 + f);
      xs[t * 33 + f + 0] = fv.x;
      xs[t * 33 + f + 1] = fv.y;
      xs[t * 33 + f + 2] = fv.z;
      xs[t * 33 + f + 3] = fv.w;
    }
    __syncthreads();
    #pragma unroll
    for (int v = 0; v < 6; v++) {
      int c = v * 256 + tid;         // 0..1535
      int dl = c / 48, tw = c % 48;
      u32 lo = (u32)f2bf(xs[(2 * tw) * 33 + dl]);
      u32 hi = (u32)f2bf(xs[(2 * tw + 1) * 33 + dl]);
      BsW[(size_t)(q * 32 + dl) * 48 + tw] = lo | (hi << 16);
    }
    __syncthreads();  // also drains As g2l16 on the last pass
  }

  const int l15 = lane & 15, lq = lane >> 4;
  f32x4 acc[2][6][2] = {};
  #pragma unroll
  for (int ks = 0; ks < 3; ks++) {
    int kt = ks * 32;
    bf16x8 bfr[2];
    #pragma unroll
    for (int j = 0; j < 2; j++)
      bfr[j] = *(const bf16x8*)&Bs[(w * 32 + j * 16 + l15) * SEQ + kt + lq * 8];
    #pragma unroll
    for (int f = 0; f < 2; f++)
      #pragma unroll
      for (int i = 0; i < 6; i++) {
        bf16x8 afr = *(const bf16x8*)&As0[f * SEQ * SEQ + (i * 16 + l15) * SEQ + kt + lq * 8];
        #pragma unroll
        for (int j = 0; j < 2; j++)
          acc[f][i][j] = __builtin_amdgcn_mfma_f32_16x16x32_bf16(afr, bfr[j], acc[f][i][j], 0, 0, 0);
      }
  }
  __syncthreads();  // all Bs reads done; Bs+xs region reusable

  // epilogue: per filter, re-tile through LDS then coalesced u32 stores
  u16* T = (u16*)ldsbuf;          // [96 s][130 d] (pad 130 -> conflict-free)
  u32* Tw = (u32*)ldsbuf;
  #pragma unroll
  for (int f = 0; f < 2; f++) {
    u16* dst = f ? xh : xl;
    #pragma unroll
    for (int i = 0; i < 6; i++)
      #pragma unroll
      for (int j = 0; j < 2; j++) {
        int d = w * 32 + j * 16 + l15;
        #pragma unroll
        for (int r = 0; r < 4; r++) {
          int s = i * 16 + lq * 4 + r;
          T[s * 130 + d] = f2bf(acc[f][i][j][r]);
        }
      }
    __syncthreads();
    // coalesced copy-out: 96 rows x 64 u32 words, 256 B contiguous per wave-row
    u32* outw = (u32*)(dst + (size_t)b * SEQ * DM + d0);
    #pragma unroll
    for (int v = 0; v < 24; v++) {
      int c = v * 256 + tid;        // 0..6143
      int s = c >> 6, dp = c & 63;
      outw[s * 256 + dp] = Tw[s * 65 + dp];
    }
    __syncthreads();
  }
}

// ---------- K3: proj GEMM (round-0 proven structure) ----------
// C[M,512] = A[M,512]bf16 @ Wt[512,512]^T + bias. 128x128 tile, 4 waves.
__global__ void __launch_bounds__(256) gemm_proj_mfma_k(
    const u16* __restrict__ xl, const u16* __restrict__ xh,
    const u16* __restrict__ Wlt, const u16* __restrict__ Wht,
    const float* __restrict__ bl, const float* __restrict__ bh,
    u16* __restrict__ yl, u16* __restrict__ yh) {
  const u16* A = blockIdx.z ? xh : xl;
  const u16* Bt = blockIdx.z ? Wht : Wlt;
  const float* bias = blockIdx.z ? bh : bl;
  u16* C = blockIdx.z ? yh : yl;

  __shared__ __align__(16) u16 As[128 * 32];
  __shared__ __align__(16) u16 Bs[128 * 32];
  const int m0 = blockIdx.x * 128;
  const int n0 = blockIdx.y * 128;
  const int tid = threadIdx.x;
  const int lane = tid & 63;
  const int w = tid >> 6;
  const int wm = w & 1, wn = w >> 1;  // 2x2 waves, each 64x64
  const int l15 = lane & 15;
  const int lq = lane >> 4;  // 0..3

  f32x4 acc[4][4] = {};

  for (int kt = 0; kt < 512; kt += 32) {
    #pragma unroll
    for (int r = 0; r < 2; r++) {
      int chunk = r * 256 + tid;      // 16B chunk id (0..511)
      int row = chunk >> 2;           // 0..127
      int ce = (chunk & 3) << 3;      // elem offset within 32-k row
      u32 lo = (u32)((r * 256 + w * 64) << 4);  // wave-uniform LDS byte base
      g2l16(A + (size_t)(m0 + row) * 512 + kt + ce, (char*)As + lo);
      g2l16(Bt + (size_t)(n0 + row) * 512 + kt + ce, (char*)Bs + lo);
    }
    __syncthreads();
    bf16x8 af[4], bf[4];
    #pragma unroll
    for (int i = 0; i < 4; i++)
      af[i] = *(const bf16x8*)&As[(wm * 64 + i * 16 + l15) * 32 + lq * 8];
    #pragma unroll
    for (int j = 0; j < 4; j++)
      bf[j] = *(const bf16x8*)&Bs[(wn * 64 + j * 16 + l15) * 32 + lq * 8];
    #pragma unroll
    for (int i = 0; i < 4; i++)
      #pragma unroll
      for (int j = 0; j < 4; j++)
        acc[i][j] = __builtin_amdgcn_mfma_f32_16x16x32_bf16(af[i], bf[j], acc[i][j], 0, 0, 0);
    __syncthreads();
  }

  #pragma unroll
  for (int j = 0; j < 4; j++) {
    int n = n0 + wn * 64 + j * 16 + l15;
    float bv = bias[n];
    #pragma unroll
    for (int i = 0; i < 4; i++) {
      int mrow = m0 + wm * 64 + i * 16 + lq * 4;
      #pragma unroll
      for (int r = 0; r < 4; r++)
        C[(size_t)(mrow + r) * 512 + n] = f2bf(acc[i][j][r] + bv);
    }
  }
}

// ---------- K4: gate GEMM (round-0 proven structure), sigmoid -> g bf16 ----------
__global__ void __launch_bounds__(256) gemm_gate_mfma_k(
    const u16* __restrict__ yl, const u16* __restrict__ yh,
    const u16* __restrict__ Wgt, const float* __restrict__ bg,
    u16* __restrict__ g) {
  __shared__ __align__(16) u16 As[128 * 32];
  __shared__ __align__(16) u16 Bs[128 * 32];
  const int m0 = blockIdx.x * 128;
  const int n0 = blockIdx.y * 128;
  const int tid = threadIdx.x;
  const int lane = tid & 63;
  const int w = tid >> 6;
  const int wm = w & 1, wn = w >> 1;
  const int l15 = lane & 15;
  const int lq = lane >> 4;

  f32x4 acc[4][4] = {};

  for (int kt = 0; kt < 1024; kt += 32) {
    const u16* Ak = (kt < 512) ? yl : yh;
    int ka = kt & 511;
    #pragma unroll
    for (int r = 0; r < 2; r++) {
      int chunk = r * 256 + tid;
      int row = chunk >> 2;
      int ce = (chunk & 3) << 3;
      u32 lo = (u32)((r * 256 + w * 64) << 4);
      g2l16(Ak + (size_t)(m0 + row) * 512 + ka + ce, (char*)As + lo);
      g2l16(Wgt + (size_t)(n0 + row) * 1024 + kt + ce, (char*)Bs + lo);
    }
    __syncthreads();
    bf16x8 af[4], bf[4];
    #pragma unroll
    for (int i = 0; i < 4; i++)
      af[i] = *(const bf16x8*)&As[(wm * 64 + i * 16 + l15) * 32 + lq * 8];
    #pragma unroll
    for (int j = 0; j < 4; j++)
      bf[j] = *(const bf16x8*)&Bs[(wn * 64 + j * 16 + l15) * 32 + lq * 8];
    #pragma unroll
    for (int i = 0; i < 4; i++)
      #pragma unroll
      for (int j = 0; j < 4; j++)
        acc[i][j] = __builtin_amdgcn_mfma_f32_16x16x32_bf16(af[i], bf[j], acc[i][j], 0, 0, 0);
    __syncthreads();
  }

  #pragma unroll
  for (int j = 0; j < 4; j++) {
    int n = n0 + wn * 64 + j * 16 + l15;
    float bv = bg[n];
    #pragma unroll
    for (int i = 0; i < 4; i++) {
      int mrow = m0 + wm * 64 + i * 16 + lq * 4;
      #pragma unroll
      for (int r = 0; r < 4; r++) {
        float z = acc[i][j][r] + bv;
        g[(size_t)(mrow + r) * 512 + n] = f2bf(1.0f / (1.0f + __expf(-z)));
      }
    }
  }
}

// ---------- K5: y = x + g*yl + (1-g)*yh ; LayerNorm (one wave per row) ----------
__global__ void __launch_bounds__(256) final_ln_k(
    const float* __restrict__ x, const u16* __restrict__ yl,
    const u16* __restrict__ yh, const u16* __restrict__ g,
    const float* __restrict__ gamma, const float* __restrict__ beta,
    float* __restrict__ out) {
  const int wave = threadIdx.x >> 6;
  const int lane = threadIdx.x & 63;
  const size_t row = (size_t)blockIdx.x * 4 + wave;
  const size_t base = row * 512 + lane * 8;
  const int e = lane * 8;

  float4 xv0 = *(const float4*)(x + base);
  float4 xv1 = *(const float4*)(x + base + 4);
  u16x8 lv = *(const u16x8*)(yl + base);
  u16x8 hv = *(const u16x8*)(yh + base);
  u16x8 gv = *(const u16x8*)(g + base);

  float v[8];
  const float xs[8] = {xv0.x, xv0.y, xv0.z, xv0.w, xv1.x, xv1.y, xv1.z, xv1.w};
  float sum = 0.f, sumsq = 0.f;
  #pragma unroll
  for (int k = 0; k < 8; k++) {
    float gl = bf2f(gv[k]);
    float vv = xs[k] + gl * bf2f(lv[k]) + (1.f - gl) * bf2f(hv[k]);
    v[k] = vv;
    sum += vv;
    sumsq += vv * vv;
  }
  #pragma unroll
  for (int off = 32; off; off >>= 1) {
    sum += __shfl_xor(sum, off);
    sumsq += __shfl_xor(sumsq, off);
  }
  const float mu = sum * (1.f / 512.f);
  const float var = sumsq * (1.f / 512.f) - mu * mu;
  const float inv = rsqrtf(var + 1e-5f);

  float4 gm0 = *(const float4*)(gamma + e);
  float4 gm1 = *(const float4*)(gamma + e + 4);
  float4 bt0 = *(const float4*)(beta + e);
  float4 bt1 = *(const float4*)(beta + e + 4);
  float4 o0, o1;
  o0.x = (v[0] - mu) * inv * gm0.x + bt0.x;
  o0.y = (v[1] - mu) * inv * gm0.y + bt0.y;
  o0.z = (v[2] - mu) * inv * gm0.z + bt0.z;
  o0.w = (v[3] - mu) * inv * gm0.w + bt0.w;
  o1.x = (v[4] - mu) * inv * gm1.x + bt1.x;
  o1.y = (v[5] - mu) * inv * gm1.y + bt1.y;
  o1.z = (v[6] - mu) * inv * gm1.z + bt1.z;
  o1.w = (v[7] - mu) * inv * gm1.w + bt1.w;
  *(float4*)(out + base) = o0;
  *(float4*)(out + base + 4) = o1;
}

extern "C" void kernel_launch(void* const* d_in, const int* in_sizes, int n_in,
                              void* d_out, int out_size, void* d_ws, size_t ws_size,
                              hipStream_t stream) {
  const float* x     = (const float*)d_in[0];
  const float* fw    = (const float*)d_in[1];
  const float* Wl    = (const float*)d_in[2];
  const float* bl    = (const float*)d_in[3];
  const float* Wh    = (const float*)d_in[4];
  const float* bh    = (const float*)d_in[5];
  const float* Wg    = (const float*)d_in[6];
  const float* bg    = (const float*)d_in[7];
  const float* gamma = (const float*)d_in[8];
  const float* beta  = (const float*)d_in[9];
  float* out = (float*)d_out;

  char* ws = (char*)d_ws;
  u16* FlB = (u16*)ws;                      // 96*96 bf16
  u16* FhB = FlB + SEQ * SEQ;
  u16* Wlt = (u16*)(ws + 64 * 1024);        // 512x512 bf16 [N][K]
  u16* Wht = Wlt + 512 * 512;
  u16* Wgt = Wht + 512 * 512;               // 512x1024 [N][K]
  size_t tsz = (size_t)MROWS * 512;         // 25165824 elems
  u16* xl = (u16*)(ws + 4 * 1024 * 1024);
  u16* xh = xl + tsz;
  u16* yl = xh + tsz;
  u16* yh = yl + tsz;
  u16* gbuf = xl;  // xl dead after proj GEMM -> reuse for gate output

  build_filters_k<<<dim3(36), dim3(256), 0, stream>>>(fw, FlB, FhB);
  transpose_w_k<<<dim3(16, 16), dim3(256), 0, stream>>>(Wl, Wlt, 512, 512);
  transpose_w_k<<<dim3(16, 16), dim3(256), 0, stream>>>(Wh, Wht, 512, 512);
  transpose_w_k<<<dim3(32, 16), dim3(256), 0, stream>>>(Wg, Wgt, 1024, 512);
  filter_fused_k<<<dim3(NBATCH, DM / 128), dim3(256), 0, stream>>>(x, FlB, FhB, xl, xh);
  gemm_proj_mfma_k<<<dim3(MROWS / 128, 4, 2), dim3(256), 0, stream>>>(
      xl, xh, Wlt, Wht, bl, bh, yl, yh);
  gemm_gate_mfma_k<<<dim3(MROWS / 128, 4), dim3(256), 0, stream>>>(yl, yh, Wgt, bg, gbuf);
  final_ln_k<<<dim3(MROWS / 4), dim3(256), 0, stream>>>(x, yl, yh, gbuf, gamma, beta, out);
}